// Round 11
// baseline (257.936 us; speedup 1.0000x reference)
//
#include <hip/hip_runtime.h>

#define N_GENE 4762
#define N_CELL 847
#define NEDGE  200000
#define D      256
#define NPART  64     // hist/scatter chunks
#define MAGIC  0x5EEDF00D

typedef __attribute__((ext_vector_type(8))) short short8;            // 8 bf16
typedef __attribute__((ext_vector_type(8))) unsigned short ushort8v; // 16B load
typedef __attribute__((ext_vector_type(4))) float f32x4;

// ---- histogram segment layout (bins, concatenated) ----
#define S_G_OUT 0                      // [4762] g2c_src degrees (genes)
#define S_C_IN  (S_G_OUT + N_GENE)     // [847]  g2c_dst degrees (cells)
#define S_C_OUT (S_C_IN + N_CELL)      // [847]  c2g_src degrees (cells)
#define S_G_IN  (S_C_OUT + N_CELL)     // [4762] c2g_dst degrees (genes)
#define NBINS   (S_G_IN + N_GENE)      // 11218

#define ALIGN8(x) (((x) + 7) & ~7)

// gemm grid
#define CT ((N_CELL + 15) / 16)        // 53
#define GT ((N_GENE + 15) / 16)        // 298
#define GB ((CT + GT + 3) / 4)         // 88 blocks

// ---- workspace layout (4-byte slots) ----
#define A_DEG      0                          // int[11218]
#define A_NRM      (A_DEG + NBINS)            // float[11218]
#define A_OFFS_C   (A_NRM + NBINS)            // int[848]
#define A_OFFS_G   (A_OFFS_C + N_CELL + 1)    // int[4763]
#define A_SORT_C   ALIGN8(A_OFFS_G + N_GENE + 1) // int2[200000]
#define A_SORT_G   (A_SORT_C + 2 * NEDGE)     // int2[200000]
#define A_PART     (A_SORT_G + 2 * NEDGE)     // int[64*11218]
#define A_SG       (A_PART + NPART * NBINS)   // float[4762]
#define A_SC       (A_SG + N_GENE)            // float[847]
#define A_FLG0     (A_SC + N_CELL)            // int[128]  k_pre barrier flags
#define A_FLG1     (A_FLG0 + 2 * NPART)       // int[GB]   k_gemm2 barrier flags
// bf16 regions (ushort; slot = count/2), 16B-aligned
#define A_GENE_BF  ALIGN8(A_FLG1 + GB)
#define A_CELL_BF  ALIGN8(A_GENE_BF + N_GENE * D / 2)
#define A_WT1_BF   ALIGN8(A_CELL_BF + N_CELL * D / 2)
#define A_WT2_BF   ALIGN8(A_WT1_BF + D * D / 2)
#define A_AGGC_BF  ALIGN8(A_WT2_BF + D * D / 2)
#define A_AGGG_BF  ALIGN8(A_AGGC_BF + N_CELL * D / 2)

__device__ __forceinline__ unsigned short f2bf(float f) {
    unsigned u = __float_as_uint(f);
    u = (u + 0x7FFFu + ((u >> 16) & 1u)) >> 16;    // RNE
    return (unsigned short)u;
}
__device__ __forceinline__ float bf2f(unsigned short b) {
    return __uint_as_float(((unsigned)b) << 16);
}

// All-blocks-resident flag barrier. Arrival = release STORE; poll = relaxed
// atomic LOAD (no RMW — round 10 showed RMW-polling serializes ~100µs).
// flags[] comes from the 0xAA-poisoned ws (init != MAGIC on every replay).
__device__ __forceinline__ void grid_barrier(int* flags, int nblk) {
    __threadfence();
    __syncthreads();
    if (threadIdx.x == 0)
        __hip_atomic_store(&flags[blockIdx.x], MAGIC, __ATOMIC_RELEASE,
                           __HIP_MEMORY_SCOPE_AGENT);
    for (int i = threadIdx.x; i < nblk; i += blockDim.x) {
        while (__hip_atomic_load(&flags[i], __ATOMIC_RELAXED,
                                 __HIP_MEMORY_SCOPE_AGENT) != MAGIC)
            __builtin_amdgcn_s_sleep(2);
    }
    __syncthreads();
    __threadfence();   // acquire: invalidate caches before reading peers' data
}

// blocks 0..63: per-block LDS histograms -> partial[b][j]
// blocks 64..127: bf16 conversions + W transposes (independent work)
// then: flag barrier; reduce partials -> deg,nrm; partial := exclusive prefix.
__global__ __launch_bounds__(1024) void k_pre(
        const int* __restrict__ g2c_src, const int* __restrict__ g2c_dst,
        const int* __restrict__ c2g_src, const int* __restrict__ c2g_dst,
        const float* __restrict__ gene_emb, const float* __restrict__ cell_emb,
        const float* __restrict__ W_g2c, const float* __restrict__ W_c2g,
        int* __restrict__ partial, int* __restrict__ flags,
        int* __restrict__ deg, float* __restrict__ nrm,
        unsigned short* __restrict__ gene_bf, unsigned short* __restrict__ cell_bf,
        unsigned short* __restrict__ wt1, unsigned short* __restrict__ wt2) {
    __shared__ int sh[NBINS];
    int B = blockIdx.x, T = threadIdx.x;
    if (B < NPART) {
        for (int j = T; j < NBINS; j += 1024) sh[j] = 0;
        __syncthreads();
        const int chunk = (NEDGE + NPART - 1) / NPART;
        int e0 = B * chunk, e1 = min(NEDGE, e0 + chunk);
        for (int e = e0 + T; e < e1; e += 1024) {
            atomicAdd(&sh[S_G_OUT + g2c_src[e]], 1);
            atomicAdd(&sh[S_C_IN  + g2c_dst[e]], 1);
            atomicAdd(&sh[S_C_OUT + c2g_src[e]], 1);
            atomicAdd(&sh[S_G_IN  + c2g_dst[e]], 1);
        }
        __syncthreads();
        int* pp = partial + B * NBINS;
        for (int j = T; j < NBINS; j += 1024) pp[j] = sh[j];
    } else {
        const int NG = N_GENE * D, NC = N_CELL * D, NW = D * D;
        const int total = NG + NC + 2 * NW;
        for (int i = (B - NPART) * 1024 + T; i < total; i += NPART * 1024) {
            if (i < NG) {
                gene_bf[i] = f2bf(gene_emb[i]);
            } else if (i < NG + NC) {
                int j = i - NG;
                cell_bf[j] = f2bf(cell_emb[j]);
            } else if (i < NG + NC + NW) {
                int j = i - NG - NC;
                wt1[j] = f2bf(W_g2c[(j & 255) * D + (j >> 8)]);
            } else {
                int j = i - NG - NC - NW;
                wt2[j] = f2bf(W_c2g[(j & 255) * D + (j >> 8)]);
            }
        }
    }
    // ---- fused reduce (was k_reduce) ----
    grid_barrier(flags, 2 * NPART);
    for (int j = B * 1024 + T; j < NBINS; j += 2 * NPART * 1024) {
        int s = 0;
        #pragma unroll
        for (int b0 = 0; b0 < NPART; b0 += 32) {
            int t[32];
            #pragma unroll
            for (int u = 0; u < 32; u++) t[u] = partial[(b0 + u) * NBINS + j];
            #pragma unroll
            for (int u = 0; u < 32; u++) { partial[(b0 + u) * NBINS + j] = s; s += t[u]; }
        }
        deg[j] = s;
        nrm[j] = rsqrtf(fmaxf((float)s, 1.0f));
    }
}

// Deterministic counting sort; each block recomputes the CSR-offset scan of its
// direction's degree segment in LDS, seeds cursors with offs+base_rank,
// places int2{src, norm_src}. grid=(NPART, 2).
__global__ __launch_bounds__(1024) void k_scatter(
        const int* __restrict__ g2c_src, const int* __restrict__ g2c_dst,
        const int* __restrict__ c2g_src, const int* __restrict__ c2g_dst,
        const int* __restrict__ deg, const int* __restrict__ partial,
        const float* __restrict__ nrm,
        int* __restrict__ offsC, int* __restrict__ offsG,
        int2* __restrict__ sortC, int2* __restrict__ sortG) {
    __shared__ int soffs[N_GENE + 1];
    __shared__ int scur[N_GENE];
    __shared__ int wsum[16];
    int T = threadIdx.x, blk = blockIdx.x, dir = blockIdx.y;
    const int* src  = dir ? c2g_src : g2c_src;
    const int* dst  = dir ? c2g_dst : g2c_dst;
    const int* dgs  = dir ? deg + S_G_IN : deg + S_C_IN;
    const float* nsv = dir ? nrm + S_C_OUT : nrm + S_G_OUT;
    int seg         = dir ? S_G_IN : S_C_IN;
    int nb          = dir ? N_GENE : N_CELL;
    int* goffs      = dir ? offsG : offsC;
    int2* sorted    = dir ? sortG : sortC;
    int per = (nb + 1023) >> 10;              // <=5
    int i0 = T * per, i1 = min(nb, i0 + per);
    int loc[5];
    int s = 0;
    for (int i = i0; i < i1; i++) { loc[i - i0] = s; s += dgs[i]; }
    int lane = T & 63, w = T >> 6;
    int t = s;
    #pragma unroll
    for (int off = 1; off < 64; off <<= 1) {
        int u = __shfl_up(t, off);
        if (lane >= off) t += u;
    }
    if (lane == 63) wsum[w] = t;
    __syncthreads();
    if (w == 0 && lane < 16) {
        int x = wsum[lane];
        #pragma unroll
        for (int off = 1; off < 16; off <<= 1) {
            int u = __shfl_up(x, off);
            if (lane >= off) x += u;
        }
        wsum[lane] = x;
    }
    __syncthreads();
    int wbase = w ? wsum[w - 1] : 0;
    int excl = wbase + t - s;
    for (int i = i0; i < i1; i++) soffs[i] = excl + loc[i - i0];
    if (T == 1023) soffs[nb] = excl + s;
    __syncthreads();
    if (blk == 0)
        for (int j = T; j <= nb; j += 1024) goffs[j] = soffs[j];
    const int* basep = partial + blk * NBINS + seg;
    for (int j = T; j < nb; j += 1024) scur[j] = soffs[j] + basep[j];
    __syncthreads();
    const int chunk = (NEDGE + NPART - 1) / NPART;
    int e0 = blk * chunk, e1 = min(NEDGE, e0 + chunk);
    for (int e = e0 + T; e < e1; e += 1024) {
        int d = dst[e], sv = src[e];
        float nv = nsv[sv];
        int pos = atomicAdd(&scur[d], 1);
        sorted[pos] = make_int2(sv, __float_as_int(nv));
    }
}

// Aggregation with paired-row 16B loads: lane = (half = lane>>5, li = lane&31);
// one ushort8 load fetches 2 edge rows per instruction, lane owns 8 columns;
// xor-32 shuffle folds the halves. Blocks 0..846: block-per-cell. Rest: wave-per-gene.
__global__ __launch_bounds__(256) void k_agg(
        const unsigned short* __restrict__ gene_bf,
        const unsigned short* __restrict__ cell_bf,
        const int2* __restrict__ sortC, const int2* __restrict__ sortG,
        const int* __restrict__ offsC, const int* __restrict__ offsG,
        const float* __restrict__ nrm,
        unsigned short* __restrict__ aggC, unsigned short* __restrict__ aggG) {
    __shared__ int   sidx[4][64];
    __shared__ float snrm[4][64];
    __shared__ float pacc[4][256];
    int w = threadIdx.x >> 6, lane = threadIdx.x & 63;
    int half = lane >> 5, li = lane & 31;
    int B = blockIdx.x;
    bool isCell = B < N_CELL;

    int e0, e1;
    const unsigned short* emb;
    const int2* sorted;
    int node;
    if (isCell) {
        node = B;
        int f0 = offsC[node], f1 = offsC[node + 1];
        int ne = f1 - f0, nw = (ne + 3) >> 2;
        e0 = f0 + w * nw; e1 = min(f1, e0 + nw);
        emb = gene_bf; sorted = sortC;
    } else {
        node = (B - N_CELL) * 4 + w;
        if (node >= N_GENE) return;
        e0 = offsG[node]; e1 = offsG[node + 1];
        emb = cell_bf; sorted = sortG;
    }

    float acc[8];
    #pragma unroll
    for (int c = 0; c < 8; c++) acc[c] = 0.f;

    for (int base = e0; base < e1; base += 64) {
        int n = min(64, e1 - base);
        if (lane < n) {
            int2 pr = sorted[base + lane];
            sidx[w][lane] = pr.x;
            snrm[w][lane] = __int_as_float(pr.y);
        }
        // same-wave LDS write->read: program order, no barrier needed
        int i = 0;
        for (; 2 * i + 8 <= n; i += 4) {
            int j0 = 2 * i + half, j1 = 2 * i + 2 + half;
            int j2 = 2 * i + 4 + half, j3 = 2 * i + 6 + half;
            ushort8v v0 = *(const ushort8v*)&emb[sidx[w][j0] * D + li * 8];
            ushort8v v1 = *(const ushort8v*)&emb[sidx[w][j1] * D + li * 8];
            ushort8v v2 = *(const ushort8v*)&emb[sidx[w][j2] * D + li * 8];
            ushort8v v3 = *(const ushort8v*)&emb[sidx[w][j3] * D + li * 8];
            float n0 = snrm[w][j0], n1 = snrm[w][j1];
            float n2 = snrm[w][j2], n3 = snrm[w][j3];
            #pragma unroll
            for (int c = 0; c < 8; c++)
                acc[c] += bf2f(v0[c]) * n0 + bf2f(v1[c]) * n1 +
                          bf2f(v2[c]) * n2 + bf2f(v3[c]) * n3;
        }
        int npair = (n + 1) >> 1;
        for (; i < npair; i++) {
            int jj = 2 * i + half;
            bool ok = jj < n;
            int idx = ok ? sidx[w][jj] : sidx[w][0];
            float nv = ok ? snrm[w][jj] : 0.f;
            ushort8v v = *(const ushort8v*)&emb[idx * D + li * 8];
            #pragma unroll
            for (int c = 0; c < 8; c++) acc[c] += bf2f(v[c]) * nv;
        }
    }
    #pragma unroll
    for (int c = 0; c < 8; c++) acc[c] += __shfl_xor(acc[c], 32);

    if (isCell) {
        if (half == 0) {
            #pragma unroll
            for (int c = 0; c < 8; c++) pacc[w][li * 8 + c] = acc[c];
        }
        __syncthreads();
        int T = threadIdx.x;          // T = column
        float s2 = pacc[0][T] + pacc[1][T] + pacc[2][T] + pacc[3][T];
        aggC[node * D + T] = f2bf(s2 * nrm[S_C_IN + node]);
    } else {
        if (half == 0) {
            float ndv = nrm[S_G_IN + node];
            ushort8v o;
            #pragma unroll
            for (int c = 0; c < 8; c++) o[c] = f2bf(acc[c] * ndv);
            *(ushort8v*)&aggG[node * D + li * 8] = o;
        }
    }
}

// MFMA bf16 GEMM + bias + relu + fused Wp row-dot; then flag barrier and the
// fused edge-score phase. No early returns — barrier needs all blocks.
__global__ __launch_bounds__(256) void k_gemm2(
        const unsigned short* __restrict__ aggC, const unsigned short* __restrict__ aggG,
        const unsigned short* __restrict__ wt1, const unsigned short* __restrict__ wt2,
        const float* __restrict__ b_g2c, const float* __restrict__ b_c2g,
        const float* __restrict__ Wp,
        float* __restrict__ hC, float* __restrict__ hG,
        float* __restrict__ sg, float* __restrict__ sc,
        int* __restrict__ flags,
        const int* __restrict__ dsrc, const int* __restrict__ ddst,
        const float* __restrict__ bp, float* __restrict__ score) {
    int wid = blockIdx.x * 4 + (threadIdx.x >> 6);
    if (wid < CT + GT) {
        bool isCell = wid < CT;
        int tile = isCell ? wid : wid - CT;
        int m0 = tile * 16;
        int M = isCell ? N_CELL : N_GENE;
        const unsigned short* A  = isCell ? aggC : aggG;
        const unsigned short* Wt = isCell ? wt1 : wt2;
        const float* bias = isCell ? b_g2c : b_c2g;
        const float* wp   = isCell ? Wp + D : Wp;
        float* H  = isCell ? hC : hG;
        float* sv = isCell ? sc : sg;
        int lane = threadIdx.x & 63;
        int l15 = lane & 15, quad = lane >> 4;
        int arow = m0 + l15;
        if (arow >= M) arow = M - 1;
        f32x4 acc[16];
        #pragma unroll
        for (int t = 0; t < 16; t++) acc[t] = (f32x4){0.f, 0.f, 0.f, 0.f};
        #pragma unroll
        for (int k0 = 0; k0 < D; k0 += 32) {
            short8 a = *(const short8*)&A[arow * D + k0 + quad * 8];
            #pragma unroll
            for (int t = 0; t < 16; t++) {
                short8 b = *(const short8*)&Wt[(t * 16 + l15) * D + k0 + quad * 8];
                acc[t] = __builtin_amdgcn_mfma_f32_16x16x32_bf16(a, b, acc[t], 0, 0, 0);
            }
        }
        float dot[4] = {0.f, 0.f, 0.f, 0.f};
        #pragma unroll
        for (int t = 0; t < 16; t++) {
            int col = t * 16 + l15;
            float bv = bias[col], wv = wp[col];
            #pragma unroll
            for (int r = 0; r < 4; r++) {
                int row = m0 + quad * 4 + r;
                float h = fmaxf(acc[t][r] + bv, 0.f);
                if (row < M) H[row * D + col] = h;
                dot[r] += h * wv;
            }
        }
        #pragma unroll
        for (int off = 1; off < 16; off <<= 1) {
            #pragma unroll
            for (int r = 0; r < 4; r++) dot[r] += __shfl_xor(dot[r], off);
        }
        if (l15 == 0) {
            #pragma unroll
            for (int r = 0; r < 4; r++) {
                int row = m0 + quad * 4 + r;
                if (row < M) sv[row] = dot[r];
            }
        }
    }
    // ---- fused edge scores (was k_score) ----
    grid_barrier(flags, GB);
    float bp0 = bp[0];
    for (int i = blockIdx.x * 256 + threadIdx.x; i < NEDGE; i += GB * 256)
        score[i] = sg[dsrc[i]] + sc[ddst[i]] + bp0;
}

extern "C" void kernel_launch(void* const* d_in, const int* in_sizes, int n_in,
                              void* d_out, int out_size, void* d_ws, size_t ws_size,
                              hipStream_t stream) {
    const float* gene_emb = (const float*)d_in[0];
    const float* cell_emb = (const float*)d_in[1];
    const float* W_g2c    = (const float*)d_in[2];
    const float* b_g2c    = (const float*)d_in[3];
    const float* W_c2g    = (const float*)d_in[4];
    const float* b_c2g    = (const float*)d_in[5];
    const float* Wp       = (const float*)d_in[6];
    const float* bp       = (const float*)d_in[7];
    const int* g2c_src = (const int*)d_in[8];
    const int* g2c_dst = (const int*)d_in[9];
    const int* c2g_src = (const int*)d_in[10];
    const int* c2g_dst = (const int*)d_in[11];
    const int* dec_src = (const int*)d_in[12];
    const int* dec_dst = (const int*)d_in[13];

    int*   wsi = (int*)d_ws;
    float* wsf = (float*)d_ws;
    unsigned short* gene_bf = (unsigned short*)(wsi + A_GENE_BF);
    unsigned short* cell_bf = (unsigned short*)(wsi + A_CELL_BF);
    unsigned short* wt1     = (unsigned short*)(wsi + A_WT1_BF);
    unsigned short* wt2     = (unsigned short*)(wsi + A_WT2_BF);
    unsigned short* aggC    = (unsigned short*)(wsi + A_AGGC_BF);
    unsigned short* aggG    = (unsigned short*)(wsi + A_AGGG_BF);
    int2* sortC = (int2*)(wsi + A_SORT_C);
    int2* sortG = (int2*)(wsi + A_SORT_G);

    float* out = (float*)d_out;
    float* out_score = out;                      // [200000]
    float* out_hgene = out + NEDGE;              // [4762*256]
    float* out_hcell = out + NEDGE + N_GENE * D; // [847*256]

    // 1. hist + cvt, then fused reduce (load-poll barrier; 128 blocks co-resident)
    k_pre<<<2 * NPART, 1024, 0, stream>>>(g2c_src, g2c_dst, c2g_src, c2g_dst,
                                          gene_emb, cell_emb, W_g2c, W_c2g,
                                          wsi + A_PART, wsi + A_FLG0,
                                          wsi + A_DEG, wsf + A_NRM,
                                          gene_bf, cell_bf, wt1, wt2);
    // 2. counting sort (per-block LDS offset scan; publishes global offs)
    {
        dim3 grid(NPART, 2);
        k_scatter<<<grid, 1024, 0, stream>>>(g2c_src, g2c_dst, c2g_src, c2g_dst,
                                             wsi + A_DEG, wsi + A_PART, wsf + A_NRM,
                                             wsi + A_OFFS_C, wsi + A_OFFS_G,
                                             sortC, sortG);
    }
    // 3. aggregate: block-per-cell + wave-per-gene, paired-row 16B loads
    k_agg<<<N_CELL + (N_GENE + 3) / 4, 256, 0, stream>>>(
        gene_bf, cell_bf, sortC, sortG, wsi + A_OFFS_C, wsi + A_OFFS_G,
        wsf + A_NRM, aggC, aggG);
    // 4. MFMA GEMMs + bias + relu + rowdots, then fused edge scores
    k_gemm2<<<GB, 256, 0, stream>>>(aggC, aggG, wt1, wt2, b_g2c, b_c2g, Wp,
                                    out_hcell, out_hgene, wsf + A_SG, wsf + A_SC,
                                    wsi + A_FLG1, dec_src, dec_dst, bp, out_score);
}

// Round 12
// 196.148 us; speedup vs baseline: 1.3150x; 1.3150x over previous
//
#include <hip/hip_runtime.h>

#define N_GENE 4762
#define N_CELL 847
#define NEDGE  200000
#define D      256
#define NPART  64     // hist/scatter chunks

typedef __attribute__((ext_vector_type(8))) short short8;            // 8 bf16
typedef __attribute__((ext_vector_type(8))) unsigned short ushort8v; // 16B load
typedef __attribute__((ext_vector_type(4))) float f32x4;

// ---- histogram segment layout (bins, concatenated) ----
#define S_G_OUT 0                      // [4762] g2c_src degrees (genes)
#define S_C_IN  (S_G_OUT + N_GENE)     // [847]  g2c_dst degrees (cells)
#define S_C_OUT (S_C_IN + N_CELL)      // [847]  c2g_src degrees (cells)
#define S_G_IN  (S_C_OUT + N_CELL)     // [4762] c2g_dst degrees (genes)
#define NBINS   (S_G_IN + N_GENE)      // 11218

#define ALIGN8(x) (((x) + 7) & ~7)

// ---- workspace layout (4-byte slots) ----
// partial is BIN-MAJOR: partial[j*64 + b] — a bin's 64 block-counts are 2
// contiguous cache lines, so scatter blocks can derive totals/prefixes cheaply.
#define A_OFFS_C   0                          // int[848]
#define A_OFFS_G   (A_OFFS_C + N_CELL + 1)    // int[4763]
#define A_SORT_C   ALIGN8(A_OFFS_G + N_GENE + 1) // int2[200000]
#define A_SORT_G   (A_SORT_C + 2 * NEDGE)     // int2[200000]
#define A_PART     (A_SORT_G + 2 * NEDGE)     // int[11218*64] bin-major
#define A_SG       (A_PART + NBINS * NPART)   // float[4762]
#define A_SC       (A_SG + N_GENE)            // float[847]
// bf16 regions (ushort; slot = count/2), 16B-aligned
#define A_GENE_BF  ALIGN8(A_SC + N_CELL)
#define A_CELL_BF  ALIGN8(A_GENE_BF + N_GENE * D / 2)
#define A_WT1_BF   ALIGN8(A_CELL_BF + N_CELL * D / 2)
#define A_WT2_BF   ALIGN8(A_WT1_BF + D * D / 2)
#define A_AGGC_BF  ALIGN8(A_WT2_BF + D * D / 2)
#define A_AGGG_BF  ALIGN8(A_AGGC_BF + N_CELL * D / 2)

__device__ __forceinline__ unsigned short f2bf(float f) {
    unsigned u = __float_as_uint(f);
    u = (u + 0x7FFFu + ((u >> 16) & 1u)) >> 16;    // RNE
    return (unsigned short)u;
}
__device__ __forceinline__ float bf2f(unsigned short b) {
    return __uint_as_float(((unsigned)b) << 16);
}

// blocks 0..63: per-block LDS histograms -> partial[j][b] (bin-major)
// blocks 64..127: bf16 conversions (float4-vectorized) + W transposes
__global__ __launch_bounds__(1024) void k_pre(
        const int* __restrict__ g2c_src, const int* __restrict__ g2c_dst,
        const int* __restrict__ c2g_src, const int* __restrict__ c2g_dst,
        const float* __restrict__ gene_emb, const float* __restrict__ cell_emb,
        const float* __restrict__ W_g2c, const float* __restrict__ W_c2g,
        int* __restrict__ partial,
        unsigned short* __restrict__ gene_bf, unsigned short* __restrict__ cell_bf,
        unsigned short* __restrict__ wt1, unsigned short* __restrict__ wt2) {
    __shared__ int sh[NBINS];
    int B = blockIdx.x, T = threadIdx.x;
    if (B < NPART) {
        for (int j = T; j < NBINS; j += 1024) sh[j] = 0;
        __syncthreads();
        const int chunk = (NEDGE + NPART - 1) / NPART;
        int e0 = B * chunk, e1 = min(NEDGE, e0 + chunk);
        for (int e = e0 + T; e < e1; e += 1024) {
            atomicAdd(&sh[S_G_OUT + g2c_src[e]], 1);
            atomicAdd(&sh[S_C_IN  + g2c_dst[e]], 1);
            atomicAdd(&sh[S_C_OUT + c2g_src[e]], 1);
            atomicAdd(&sh[S_G_IN  + c2g_dst[e]], 1);
        }
        __syncthreads();
        for (int j = T; j < NBINS; j += 1024) partial[j * NPART + B] = sh[j];
    } else {
        const int NGv = N_GENE * D / 4, NCv = N_CELL * D / 4, NW = D * D;
        const int total = NGv + NCv + 2 * NW;
        for (int i = (B - NPART) * 1024 + T; i < total; i += NPART * 1024) {
            if (i < NGv) {
                float4 v = ((const float4*)gene_emb)[i];
                ushort4 o = make_ushort4(f2bf(v.x), f2bf(v.y), f2bf(v.z), f2bf(v.w));
                ((ushort4*)gene_bf)[i] = o;
            } else if (i < NGv + NCv) {
                int j = i - NGv;
                float4 v = ((const float4*)cell_emb)[j];
                ushort4 o = make_ushort4(f2bf(v.x), f2bf(v.y), f2bf(v.z), f2bf(v.w));
                ((ushort4*)cell_bf)[j] = o;
            } else if (i < NGv + NCv + NW) {
                int j = i - NGv - NCv;
                wt1[j] = f2bf(W_g2c[(j & 255) * D + (j >> 8)]);
            } else {
                int j = i - NGv - NCv - NW;
                wt2[j] = f2bf(W_c2g[(j & 255) * D + (j >> 8)]);
            }
        }
    }
}

// Deterministic counting sort, no k_reduce needed: each block derives from the
// bin-major partials (L2-resident) (a) dst-bin totals for its LDS offset scan,
// (b) its own base rank sum_{b<blk}, (c) src-bin totals -> rsqrt into LDS for
// the per-edge norm embed. Places int2{src, norm_src}. grid=(NPART, 2).
__global__ __launch_bounds__(1024) void k_scatter(
        const int* __restrict__ g2c_src, const int* __restrict__ g2c_dst,
        const int* __restrict__ c2g_src, const int* __restrict__ c2g_dst,
        const int* __restrict__ partial,
        int* __restrict__ offsC, int* __restrict__ offsG,
        int2* __restrict__ sortC, int2* __restrict__ sortG) {
    __shared__ int   soffs[N_GENE + 1];
    __shared__ int   scur[N_GENE];
    __shared__ float snrmL[N_GENE];
    __shared__ int   wsum[16];
    int T = threadIdx.x, blk = blockIdx.x, dir = blockIdx.y;
    const int* src  = dir ? c2g_src : g2c_src;
    const int* dst  = dir ? c2g_dst : g2c_dst;
    int seg_dst     = dir ? S_G_IN : S_C_IN;
    int seg_src     = dir ? S_C_OUT : S_G_OUT;
    int nbd         = dir ? N_GENE : N_CELL;
    int nbs         = dir ? N_CELL : N_GENE;
    int* goffs      = dir ? offsG : offsC;
    int2* sorted    = dir ? sortG : sortC;

    // src-bin norms into LDS (column sums over 64 contiguous ints per bin)
    for (int j = T; j < nbs; j += 1024) {
        const int4* pp = (const int4*)(partial + (seg_src + j) * NPART);
        int tot = 0;
        #pragma unroll
        for (int q = 0; q < NPART / 4; q++) {
            int4 v = pp[q];
            tot += v.x + v.y + v.z + v.w;
        }
        snrmL[j] = rsqrtf(fmaxf((float)tot, 1.0f));
    }
    // dst-bin totals + this block's base rank; LDS exclusive scan -> soffs
    int per = (nbd + 1023) >> 10;              // <=5
    int i0 = T * per, i1 = min(nbd, i0 + per);
    int loc[5], bl[5];
    int s = 0;
    for (int i = i0; i < i1; i++) {
        const int* pp = partial + (seg_dst + i) * NPART;
        int tot = 0, base = 0;
        #pragma unroll
        for (int b = 0; b < NPART; b++) {
            int v = pp[b];
            tot += v;
            if (b < blk) base += v;
        }
        loc[i - i0] = s;
        bl[i - i0] = base;
        s += tot;
    }
    int lane = T & 63, w = T >> 6;
    int t = s;
    #pragma unroll
    for (int off = 1; off < 64; off <<= 1) {
        int u = __shfl_up(t, off);
        if (lane >= off) t += u;
    }
    if (lane == 63) wsum[w] = t;
    __syncthreads();
    if (w == 0 && lane < 16) {
        int x = wsum[lane];
        #pragma unroll
        for (int off = 1; off < 16; off <<= 1) {
            int u = __shfl_up(x, off);
            if (lane >= off) x += u;
        }
        wsum[lane] = x;
    }
    __syncthreads();
    int wbase = w ? wsum[w - 1] : 0;
    int excl = wbase + t - s;
    for (int i = i0; i < i1; i++) {
        soffs[i] = excl + loc[i - i0];
        scur[i]  = excl + loc[i - i0] + bl[i - i0];
    }
    if (T == 1023) soffs[nbd] = excl + s;
    __syncthreads();
    if (blk == 0)
        for (int j = T; j <= nbd; j += 1024) goffs[j] = soffs[j];
    const int chunk = (NEDGE + NPART - 1) / NPART;
    int e0 = blk * chunk, e1 = min(NEDGE, e0 + chunk);
    for (int e = e0 + T; e < e1; e += 1024) {
        int d = dst[e], sv = src[e];
        float nv = snrmL[sv];
        int pos = atomicAdd(&scur[d], 1);
        sorted[pos] = make_int2(sv, __float_as_int(nv));
    }
}

// Aggregation with paired-row 16B loads: lane = (half = lane>>5, li = lane&31);
// one ushort8 load fetches 2 edge rows, lane owns 8 columns; xor-32 folds the
// halves. dst norm comes from offs[d+1]-offs[d] (no global nrm array).
// Blocks 0..846: block-per-cell (4 waves split edges). Rest: wave-per-gene.
__global__ __launch_bounds__(256) void k_agg(
        const unsigned short* __restrict__ gene_bf,
        const unsigned short* __restrict__ cell_bf,
        const int2* __restrict__ sortC, const int2* __restrict__ sortG,
        const int* __restrict__ offsC, const int* __restrict__ offsG,
        unsigned short* __restrict__ aggC, unsigned short* __restrict__ aggG) {
    __shared__ int   sidx[4][64];
    __shared__ float snrm[4][64];
    __shared__ float pacc[4][256];
    int w = threadIdx.x >> 6, lane = threadIdx.x & 63;
    int half = lane >> 5, li = lane & 31;
    int B = blockIdx.x;
    bool isCell = B < N_CELL;

    int e0, e1, degv;
    const unsigned short* emb;
    const int2* sorted;
    int node;
    if (isCell) {
        node = B;
        int f0 = offsC[node], f1 = offsC[node + 1];
        degv = f1 - f0;
        int nw = (degv + 3) >> 2;
        e0 = f0 + w * nw; e1 = min(f1, e0 + nw);
        emb = gene_bf; sorted = sortC;
    } else {
        node = (B - N_CELL) * 4 + w;
        if (node >= N_GENE) return;
        e0 = offsG[node]; e1 = offsG[node + 1];
        degv = e1 - e0;
        emb = cell_bf; sorted = sortG;
    }

    float acc[8];
    #pragma unroll
    for (int c = 0; c < 8; c++) acc[c] = 0.f;

    for (int base = e0; base < e1; base += 64) {
        int n = min(64, e1 - base);
        if (lane < n) {
            int2 pr = sorted[base + lane];
            sidx[w][lane] = pr.x;
            snrm[w][lane] = __int_as_float(pr.y);
        }
        // same-wave LDS write->read: program order, no barrier needed
        int i = 0;
        for (; 2 * i + 8 <= n; i += 4) {
            int j0 = 2 * i + half, j1 = 2 * i + 2 + half;
            int j2 = 2 * i + 4 + half, j3 = 2 * i + 6 + half;
            ushort8v v0 = *(const ushort8v*)&emb[sidx[w][j0] * D + li * 8];
            ushort8v v1 = *(const ushort8v*)&emb[sidx[w][j1] * D + li * 8];
            ushort8v v2 = *(const ushort8v*)&emb[sidx[w][j2] * D + li * 8];
            ushort8v v3 = *(const ushort8v*)&emb[sidx[w][j3] * D + li * 8];
            float n0 = snrm[w][j0], n1 = snrm[w][j1];
            float n2 = snrm[w][j2], n3 = snrm[w][j3];
            #pragma unroll
            for (int c = 0; c < 8; c++)
                acc[c] += bf2f(v0[c]) * n0 + bf2f(v1[c]) * n1 +
                          bf2f(v2[c]) * n2 + bf2f(v3[c]) * n3;
        }
        int npair = (n + 1) >> 1;
        for (; i < npair; i++) {
            int jj = 2 * i + half;
            bool ok = jj < n;
            int idx = ok ? sidx[w][jj] : sidx[w][0];
            float nv = ok ? snrm[w][jj] : 0.f;
            ushort8v v = *(const ushort8v*)&emb[idx * D + li * 8];
            #pragma unroll
            for (int c = 0; c < 8; c++) acc[c] += bf2f(v[c]) * nv;
        }
    }
    #pragma unroll
    for (int c = 0; c < 8; c++) acc[c] += __shfl_xor(acc[c], 32);

    float ndv = rsqrtf(fmaxf((float)degv, 1.0f));
    if (isCell) {
        if (half == 0) {
            #pragma unroll
            for (int c = 0; c < 8; c++) pacc[w][li * 8 + c] = acc[c];
        }
        __syncthreads();
        int T = threadIdx.x;          // T = column
        float s2 = pacc[0][T] + pacc[1][T] + pacc[2][T] + pacc[3][T];
        aggC[node * D + T] = f2bf(s2 * ndv);
    } else {
        if (half == 0) {
            ushort8v o;
            #pragma unroll
            for (int c = 0; c < 8; c++) o[c] = f2bf(acc[c] * ndv);
            *(ushort8v*)&aggG[node * D + li * 8] = o;
        }
    }
}

// MFMA bf16 GEMM, both directions: H = relu(Agg @ W + b), fused Wp row-dot.
__global__ __launch_bounds__(256) void k_gemm2(
        const unsigned short* __restrict__ aggC, const unsigned short* __restrict__ aggG,
        const unsigned short* __restrict__ wt1, const unsigned short* __restrict__ wt2,
        const float* __restrict__ b_g2c, const float* __restrict__ b_c2g,
        const float* __restrict__ Wp,
        float* __restrict__ hC, float* __restrict__ hG,
        float* __restrict__ sg, float* __restrict__ sc) {
    const int CT = (N_CELL + 15) / 16;   // 53
    const int GT = (N_GENE + 15) / 16;   // 298
    int wid = blockIdx.x * 4 + (threadIdx.x >> 6);
    if (wid >= CT + GT) return;
    bool isCell = wid < CT;
    int tile = isCell ? wid : wid - CT;
    int m0 = tile * 16;
    int M = isCell ? N_CELL : N_GENE;
    const unsigned short* A  = isCell ? aggC : aggG;
    const unsigned short* Wt = isCell ? wt1 : wt2;
    const float* bias = isCell ? b_g2c : b_c2g;
    const float* wp   = isCell ? Wp + D : Wp;
    float* H  = isCell ? hC : hG;
    float* sv = isCell ? sc : sg;
    int lane = threadIdx.x & 63;
    int l15 = lane & 15, quad = lane >> 4;
    int arow = m0 + l15;
    if (arow >= M) arow = M - 1;
    f32x4 acc[16];
    #pragma unroll
    for (int t = 0; t < 16; t++) acc[t] = (f32x4){0.f, 0.f, 0.f, 0.f};
    #pragma unroll
    for (int k0 = 0; k0 < D; k0 += 32) {
        short8 a = *(const short8*)&A[arow * D + k0 + quad * 8];
        #pragma unroll
        for (int t = 0; t < 16; t++) {
            short8 b = *(const short8*)&Wt[(t * 16 + l15) * D + k0 + quad * 8];
            acc[t] = __builtin_amdgcn_mfma_f32_16x16x32_bf16(a, b, acc[t], 0, 0, 0);
        }
    }
    float dot[4] = {0.f, 0.f, 0.f, 0.f};
    #pragma unroll
    for (int t = 0; t < 16; t++) {
        int col = t * 16 + l15;
        float bv = bias[col], wv = wp[col];
        #pragma unroll
        for (int r = 0; r < 4; r++) {
            int row = m0 + quad * 4 + r;
            float h = fmaxf(acc[t][r] + bv, 0.f);
            if (row < M) H[row * D + col] = h;
            dot[r] += h * wv;
        }
    }
    #pragma unroll
    for (int off = 1; off < 16; off <<= 1) {
        #pragma unroll
        for (int r = 0; r < 4; r++) dot[r] += __shfl_xor(dot[r], off);
    }
    if (l15 == 0) {
        #pragma unroll
        for (int r = 0; r < 4; r++) {
            int row = m0 + quad * 4 + r;
            if (row < M) sv[row] = dot[r];
        }
    }
}

__global__ void k_score(const int* __restrict__ dsrc, const int* __restrict__ ddst,
                        const float* __restrict__ sg, const float* __restrict__ sc,
                        const float* __restrict__ bp, float* __restrict__ out) {
    int i = blockIdx.x * blockDim.x + threadIdx.x;
    if (i < NEDGE) out[i] = sg[dsrc[i]] + sc[ddst[i]] + bp[0];
}

extern "C" void kernel_launch(void* const* d_in, const int* in_sizes, int n_in,
                              void* d_out, int out_size, void* d_ws, size_t ws_size,
                              hipStream_t stream) {
    const float* gene_emb = (const float*)d_in[0];
    const float* cell_emb = (const float*)d_in[1];
    const float* W_g2c    = (const float*)d_in[2];
    const float* b_g2c    = (const float*)d_in[3];
    const float* W_c2g    = (const float*)d_in[4];
    const float* b_c2g    = (const float*)d_in[5];
    const float* Wp       = (const float*)d_in[6];
    const float* bp       = (const float*)d_in[7];
    const int* g2c_src = (const int*)d_in[8];
    const int* g2c_dst = (const int*)d_in[9];
    const int* c2g_src = (const int*)d_in[10];
    const int* c2g_dst = (const int*)d_in[11];
    const int* dec_src = (const int*)d_in[12];
    const int* dec_dst = (const int*)d_in[13];

    int*   wsi = (int*)d_ws;
    float* wsf = (float*)d_ws;
    unsigned short* gene_bf = (unsigned short*)(wsi + A_GENE_BF);
    unsigned short* cell_bf = (unsigned short*)(wsi + A_CELL_BF);
    unsigned short* wt1     = (unsigned short*)(wsi + A_WT1_BF);
    unsigned short* wt2     = (unsigned short*)(wsi + A_WT2_BF);
    unsigned short* aggC    = (unsigned short*)(wsi + A_AGGC_BF);
    unsigned short* aggG    = (unsigned short*)(wsi + A_AGGG_BF);
    int2* sortC = (int2*)(wsi + A_SORT_C);
    int2* sortG = (int2*)(wsi + A_SORT_G);

    float* out = (float*)d_out;
    float* out_score = out;                      // [200000]
    float* out_hgene = out + NEDGE;              // [4762*256]
    float* out_hcell = out + NEDGE + N_GENE * D; // [847*256]

    // 1. hist (bin-major partials) + vectorized bf16 cvt / W transpose
    k_pre<<<2 * NPART, 1024, 0, stream>>>(g2c_src, g2c_dst, c2g_src, c2g_dst,
                                          gene_emb, cell_emb, W_g2c, W_c2g,
                                          wsi + A_PART, gene_bf, cell_bf, wt1, wt2);
    // 2. counting sort w/ inline column sums (no k_reduce launch)
    {
        dim3 grid(NPART, 2);
        k_scatter<<<grid, 1024, 0, stream>>>(g2c_src, g2c_dst, c2g_src, c2g_dst,
                                             wsi + A_PART,
                                             wsi + A_OFFS_C, wsi + A_OFFS_G,
                                             sortC, sortG);
    }
    // 3. aggregate: block-per-cell + wave-per-gene, paired-row 16B loads
    k_agg<<<N_CELL + (N_GENE + 3) / 4, 256, 0, stream>>>(
        gene_bf, cell_bf, sortC, sortG, wsi + A_OFFS_C, wsi + A_OFFS_G, aggC, aggG);
    // 4. MFMA GEMMs + bias + relu + fused Wp row-dots
    {
        const int CT = (N_CELL + 15) / 16, GT = (N_GENE + 15) / 16;
        k_gemm2<<<(CT + GT + 3) / 4, 256, 0, stream>>>(aggC, aggG, wt1, wt2,
                                                       b_g2c, b_c2g, Wp,
                                                       out_hcell, out_hgene,
                                                       wsf + A_SG, wsf + A_SC);
    }
    // 5. edge scores
    k_score<<<(NEDGE + 255) / 256, 256, 0, stream>>>(dec_src, dec_dst,
                                                     wsf + A_SG, wsf + A_SC, bp, out_score);
}

// Round 13
// 170.669 us; speedup vs baseline: 1.5113x; 1.1493x over previous
//
#include <hip/hip_runtime.h>

#define N_GENE 4762
#define N_CELL 847
#define NEDGE  200000
#define D      256
#define NPART  64     // hist/scatter chunks

typedef __attribute__((ext_vector_type(8))) short short8;            // 8 bf16
typedef __attribute__((ext_vector_type(8))) unsigned short ushort8v; // 16B load
typedef __attribute__((ext_vector_type(4))) float f32x4;

// ---- histogram segment layout (bins, concatenated) ----
#define S_G_OUT 0                      // [4762] g2c_src degrees (genes)
#define S_C_IN  (S_G_OUT + N_GENE)     // [847]  g2c_dst degrees (cells)
#define S_C_OUT (S_C_IN + N_CELL)      // [847]  c2g_src degrees (cells)
#define S_G_IN  (S_C_OUT + N_CELL)     // [4762] c2g_dst degrees (genes)
#define NBINS   (S_G_IN + N_GENE)      // 11218

#define ALIGN8(x) (((x) + 7) & ~7)

// ---- workspace layout (4-byte slots) ----
// partial is BIN-MAJOR: partial[j*64 + b] — one bin's 64 block-counts are 2
// contiguous cache lines (int4-loadable in k_reduce; in-place prefix).
#define A_DEG      0                          // int[11218]
#define A_NRM      (A_DEG + NBINS)            // float[11218]
#define A_OFFS_C   (A_NRM + NBINS)            // int[848]
#define A_OFFS_G   (A_OFFS_C + N_CELL + 1)    // int[4763]
#define A_SORT_C   ALIGN8(A_OFFS_G + N_GENE + 1) // int2[200000]
#define A_SORT_G   (A_SORT_C + 2 * NEDGE)     // int2[200000]
#define A_PART     (A_SORT_G + 2 * NEDGE)     // int[11218*64] bin-major
#define A_SG       (A_PART + NBINS * NPART)   // float[4762]
#define A_SC       (A_SG + N_GENE)            // float[847]
// bf16 regions (ushort; slot = count/2), 16B-aligned
#define A_GENE_BF  ALIGN8(A_SC + N_CELL)
#define A_CELL_BF  ALIGN8(A_GENE_BF + N_GENE * D / 2)
#define A_WT1_BF   ALIGN8(A_CELL_BF + N_CELL * D / 2)
#define A_WT2_BF   ALIGN8(A_WT1_BF + D * D / 2)
#define A_AGGC_BF  ALIGN8(A_WT2_BF + D * D / 2)
#define A_AGGG_BF  ALIGN8(A_AGGC_BF + N_CELL * D / 2)

__device__ __forceinline__ unsigned short f2bf(float f) {
    unsigned u = __float_as_uint(f);
    u = (u + 0x7FFFu + ((u >> 16) & 1u)) >> 16;    // RNE
    return (unsigned short)u;
}
__device__ __forceinline__ float bf2f(unsigned short b) {
    return __uint_as_float(((unsigned)b) << 16);
}

// blocks 0..63: per-block LDS histograms -> partial[j][b] (bin-major)
// blocks 64..127: bf16 conversions (float4-vectorized) + W transposes
__global__ __launch_bounds__(1024) void k_pre(
        const int* __restrict__ g2c_src, const int* __restrict__ g2c_dst,
        const int* __restrict__ c2g_src, const int* __restrict__ c2g_dst,
        const float* __restrict__ gene_emb, const float* __restrict__ cell_emb,
        const float* __restrict__ W_g2c, const float* __restrict__ W_c2g,
        int* __restrict__ partial,
        unsigned short* __restrict__ gene_bf, unsigned short* __restrict__ cell_bf,
        unsigned short* __restrict__ wt1, unsigned short* __restrict__ wt2) {
    __shared__ int sh[NBINS];
    int B = blockIdx.x, T = threadIdx.x;
    if (B < NPART) {
        for (int j = T; j < NBINS; j += 1024) sh[j] = 0;
        __syncthreads();
        const int chunk = (NEDGE + NPART - 1) / NPART;
        int e0 = B * chunk, e1 = min(NEDGE, e0 + chunk);
        for (int e = e0 + T; e < e1; e += 1024) {
            atomicAdd(&sh[S_G_OUT + g2c_src[e]], 1);
            atomicAdd(&sh[S_C_IN  + g2c_dst[e]], 1);
            atomicAdd(&sh[S_C_OUT + c2g_src[e]], 1);
            atomicAdd(&sh[S_G_IN  + c2g_dst[e]], 1);
        }
        __syncthreads();
        for (int j = T; j < NBINS; j += 1024) partial[j * NPART + B] = sh[j];
    } else {
        const int NGv = N_GENE * D / 4, NCv = N_CELL * D / 4, NW = D * D;
        const int total = NGv + NCv + 2 * NW;
        for (int i = (B - NPART) * 1024 + T; i < total; i += NPART * 1024) {
            if (i < NGv) {
                float4 v = ((const float4*)gene_emb)[i];
                ushort4 o = make_ushort4(f2bf(v.x), f2bf(v.y), f2bf(v.z), f2bf(v.w));
                ((ushort4*)gene_bf)[i] = o;
            } else if (i < NGv + NCv) {
                int j = i - NGv;
                float4 v = ((const float4*)cell_emb)[j];
                ushort4 o = make_ushort4(f2bf(v.x), f2bf(v.y), f2bf(v.z), f2bf(v.w));
                ((ushort4*)cell_bf)[j] = o;
            } else if (i < NGv + NCv + NW) {
                int j = i - NGv - NCv;
                wt1[j] = f2bf(W_g2c[(j & 255) * D + (j >> 8)]);
            } else {
                int j = i - NGv - NCv - NW;
                wt2[j] = f2bf(W_c2g[(j & 255) * D + (j >> 8)]);
            }
        }
    }
}

// Bin-major reduce: thread per bin reads its 64 contiguous partials (int4),
// converts them to an exclusive prefix in place, writes deg + nrm.
__global__ void k_reduce(int* __restrict__ partial, int* __restrict__ deg,
                         float* __restrict__ nrm) {
    int j = blockIdx.x * blockDim.x + threadIdx.x;
    if (j < NBINS) {
        int4* pp = (int4*)(partial + j * NPART);
        int s = 0;
        #pragma unroll
        for (int q = 0; q < NPART / 4; q++) {
            int4 v = pp[q];
            int t0 = v.x, t1 = v.y, t2 = v.z, t3 = v.w;
            v.x = s; s += t0;
            v.y = s; s += t1;
            v.z = s; s += t2;
            v.w = s; s += t3;
            pp[q] = v;
        }
        deg[j] = s;
        nrm[j] = rsqrtf(fmaxf((float)s, 1.0f));
    }
}

// Deterministic counting sort; each block recomputes the CSR-offset scan of its
// direction's degree segment in LDS, seeds cursors with offs + its base rank
// (bin-major prefix at column blk), places int2{src, norm_src}. grid=(NPART,2).
__global__ __launch_bounds__(1024) void k_scatter(
        const int* __restrict__ g2c_src, const int* __restrict__ g2c_dst,
        const int* __restrict__ c2g_src, const int* __restrict__ c2g_dst,
        const int* __restrict__ deg, const int* __restrict__ partial,
        const float* __restrict__ nrm,
        int* __restrict__ offsC, int* __restrict__ offsG,
        int2* __restrict__ sortC, int2* __restrict__ sortG) {
    __shared__ int soffs[N_GENE + 1];
    __shared__ int scur[N_GENE];
    __shared__ int wsum[16];
    int T = threadIdx.x, blk = blockIdx.x, dir = blockIdx.y;
    const int* src  = dir ? c2g_src : g2c_src;
    const int* dst  = dir ? c2g_dst : g2c_dst;
    const int* dgs  = dir ? deg + S_G_IN : deg + S_C_IN;
    const float* nsv = dir ? nrm + S_C_OUT : nrm + S_G_OUT;
    int seg         = dir ? S_G_IN : S_C_IN;
    int nb          = dir ? N_GENE : N_CELL;
    int* goffs      = dir ? offsG : offsC;
    int2* sorted    = dir ? sortG : sortC;
    // exclusive LDS scan of dgs[0..nb)
    int per = (nb + 1023) >> 10;              // <=5
    int i0 = T * per, i1 = min(nb, i0 + per);
    int loc[5];
    int s = 0;
    for (int i = i0; i < i1; i++) { loc[i - i0] = s; s += dgs[i]; }
    int lane = T & 63, w = T >> 6;
    int t = s;
    #pragma unroll
    for (int off = 1; off < 64; off <<= 1) {
        int u = __shfl_up(t, off);
        if (lane >= off) t += u;
    }
    if (lane == 63) wsum[w] = t;
    __syncthreads();
    if (w == 0 && lane < 16) {
        int x = wsum[lane];
        #pragma unroll
        for (int off = 1; off < 16; off <<= 1) {
            int u = __shfl_up(x, off);
            if (lane >= off) x += u;
        }
        wsum[lane] = x;
    }
    __syncthreads();
    int wbase = w ? wsum[w - 1] : 0;
    int excl = wbase + t - s;
    for (int i = i0; i < i1; i++) soffs[i] = excl + loc[i - i0];
    if (T == 1023) soffs[nb] = excl + s;
    __syncthreads();
    if (blk == 0)
        for (int j = T; j <= nb; j += 1024) goffs[j] = soffs[j];
    // base rank: bin-major exclusive prefix, column blk
    const int* basep = partial + seg * NPART + blk;
    for (int j = T; j < nb; j += 1024) scur[j] = soffs[j] + basep[j * NPART];
    __syncthreads();
    const int chunk = (NEDGE + NPART - 1) / NPART;
    int e0 = blk * chunk, e1 = min(NEDGE, e0 + chunk);
    for (int e = e0 + T; e < e1; e += 1024) {
        int d = dst[e], sv = src[e];
        float nv = nsv[sv];
        int pos = atomicAdd(&scur[d], 1);
        sorted[pos] = make_int2(sv, __float_as_int(nv));
    }
}

// Aggregation with paired-row 16B loads: lane = (half = lane>>5, li = lane&31);
// one ushort8 load fetches 2 edge rows, lane owns 8 columns; xor-32 folds the
// halves. Blocks 0..846: block-per-cell (4 waves split edges). Rest: wave-per-gene.
__global__ __launch_bounds__(256) void k_agg(
        const unsigned short* __restrict__ gene_bf,
        const unsigned short* __restrict__ cell_bf,
        const int2* __restrict__ sortC, const int2* __restrict__ sortG,
        const int* __restrict__ offsC, const int* __restrict__ offsG,
        const float* __restrict__ nrm,
        unsigned short* __restrict__ aggC, unsigned short* __restrict__ aggG) {
    __shared__ int   sidx[4][64];
    __shared__ float snrm[4][64];
    __shared__ float pacc[4][256];
    int w = threadIdx.x >> 6, lane = threadIdx.x & 63;
    int half = lane >> 5, li = lane & 31;
    int B = blockIdx.x;
    bool isCell = B < N_CELL;

    int e0, e1;
    const unsigned short* emb;
    const int2* sorted;
    int node;
    float ndv;
    if (isCell) {
        node = B;
        int f0 = offsC[node], f1 = offsC[node + 1];
        int nw = (f1 - f0 + 3) >> 2;
        e0 = f0 + w * nw; e1 = min(f1, e0 + nw);
        emb = gene_bf; sorted = sortC;
        ndv = nrm[S_C_IN + node];
    } else {
        node = (B - N_CELL) * 4 + w;
        if (node >= N_GENE) return;
        e0 = offsG[node]; e1 = offsG[node + 1];
        emb = cell_bf; sorted = sortG;
        ndv = nrm[S_G_IN + node];
    }

    float acc[8];
    #pragma unroll
    for (int c = 0; c < 8; c++) acc[c] = 0.f;

    for (int base = e0; base < e1; base += 64) {
        int n = min(64, e1 - base);
        if (lane < n) {
            int2 pr = sorted[base + lane];
            sidx[w][lane] = pr.x;
            snrm[w][lane] = __int_as_float(pr.y);
        }
        // same-wave LDS write->read: program order, no barrier needed
        int i = 0;
        for (; 2 * i + 8 <= n; i += 4) {
            int j0 = 2 * i + half, j1 = 2 * i + 2 + half;
            int j2 = 2 * i + 4 + half, j3 = 2 * i + 6 + half;
            ushort8v v0 = *(const ushort8v*)&emb[sidx[w][j0] * D + li * 8];
            ushort8v v1 = *(const ushort8v*)&emb[sidx[w][j1] * D + li * 8];
            ushort8v v2 = *(const ushort8v*)&emb[sidx[w][j2] * D + li * 8];
            ushort8v v3 = *(const ushort8v*)&emb[sidx[w][j3] * D + li * 8];
            float n0 = snrm[w][j0], n1 = snrm[w][j1];
            float n2 = snrm[w][j2], n3 = snrm[w][j3];
            #pragma unroll
            for (int c = 0; c < 8; c++)
                acc[c] += bf2f(v0[c]) * n0 + bf2f(v1[c]) * n1 +
                          bf2f(v2[c]) * n2 + bf2f(v3[c]) * n3;
        }
        int npair = (n + 1) >> 1;
        for (; i < npair; i++) {
            int jj = 2 * i + half;
            bool ok = jj < n;
            int idx = ok ? sidx[w][jj] : sidx[w][0];
            float nv = ok ? snrm[w][jj] : 0.f;
            ushort8v v = *(const ushort8v*)&emb[idx * D + li * 8];
            #pragma unroll
            for (int c = 0; c < 8; c++) acc[c] += bf2f(v[c]) * nv;
        }
    }
    #pragma unroll
    for (int c = 0; c < 8; c++) acc[c] += __shfl_xor(acc[c], 32);

    if (isCell) {
        if (half == 0) {
            #pragma unroll
            for (int c = 0; c < 8; c++) pacc[w][li * 8 + c] = acc[c];
        }
        __syncthreads();
        int T = threadIdx.x;          // T = column
        float s2 = pacc[0][T] + pacc[1][T] + pacc[2][T] + pacc[3][T];
        aggC[node * D + T] = f2bf(s2 * ndv);
    } else {
        if (half == 0) {
            ushort8v o;
            #pragma unroll
            for (int c = 0; c < 8; c++) o[c] = f2bf(acc[c] * ndv);
            *(ushort8v*)&aggG[node * D + li * 8] = o;
        }
    }
}

// MFMA bf16 GEMM, both directions: H = relu(Agg @ W + b), fused Wp row-dot.
__global__ __launch_bounds__(256) void k_gemm2(
        const unsigned short* __restrict__ aggC, const unsigned short* __restrict__ aggG,
        const unsigned short* __restrict__ wt1, const unsigned short* __restrict__ wt2,
        const float* __restrict__ b_g2c, const float* __restrict__ b_c2g,
        const float* __restrict__ Wp,
        float* __restrict__ hC, float* __restrict__ hG,
        float* __restrict__ sg, float* __restrict__ sc) {
    const int CT = (N_CELL + 15) / 16;   // 53
    const int GT = (N_GENE + 15) / 16;   // 298
    int wid = blockIdx.x * 4 + (threadIdx.x >> 6);
    if (wid >= CT + GT) return;
    bool isCell = wid < CT;
    int tile = isCell ? wid : wid - CT;
    int m0 = tile * 16;
    int M = isCell ? N_CELL : N_GENE;
    const unsigned short* A  = isCell ? aggC : aggG;
    const unsigned short* Wt = isCell ? wt1 : wt2;
    const float* bias = isCell ? b_g2c : b_c2g;
    const float* wp   = isCell ? Wp + D : Wp;
    float* H  = isCell ? hC : hG;
    float* sv = isCell ? sc : sg;
    int lane = threadIdx.x & 63;
    int l15 = lane & 15, quad = lane >> 4;
    int arow = m0 + l15;
    if (arow >= M) arow = M - 1;
    f32x4 acc[16];
    #pragma unroll
    for (int t = 0; t < 16; t++) acc[t] = (f32x4){0.f, 0.f, 0.f, 0.f};
    #pragma unroll
    for (int k0 = 0; k0 < D; k0 += 32) {
        short8 a = *(const short8*)&A[arow * D + k0 + quad * 8];
        #pragma unroll
        for (int t = 0; t < 16; t++) {
            short8 b = *(const short8*)&Wt[(t * 16 + l15) * D + k0 + quad * 8];
            acc[t] = __builtin_amdgcn_mfma_f32_16x16x32_bf16(a, b, acc[t], 0, 0, 0);
        }
    }
    float dot[4] = {0.f, 0.f, 0.f, 0.f};
    #pragma unroll
    for (int t = 0; t < 16; t++) {
        int col = t * 16 + l15;
        float bv = bias[col], wv = wp[col];
        #pragma unroll
        for (int r = 0; r < 4; r++) {
            int row = m0 + quad * 4 + r;
            float h = fmaxf(acc[t][r] + bv, 0.f);
            if (row < M) H[row * D + col] = h;
            dot[r] += h * wv;
        }
    }
    #pragma unroll
    for (int off = 1; off < 16; off <<= 1) {
        #pragma unroll
        for (int r = 0; r < 4; r++) dot[r] += __shfl_xor(dot[r], off);
    }
    if (l15 == 0) {
        #pragma unroll
        for (int r = 0; r < 4; r++) {
            int row = m0 + quad * 4 + r;
            if (row < M) sv[row] = dot[r];
        }
    }
}

__global__ void k_score(const int* __restrict__ dsrc, const int* __restrict__ ddst,
                        const float* __restrict__ sg, const float* __restrict__ sc,
                        const float* __restrict__ bp, float* __restrict__ out) {
    int i = blockIdx.x * blockDim.x + threadIdx.x;
    if (i < NEDGE) out[i] = sg[dsrc[i]] + sc[ddst[i]] + bp[0];
}

extern "C" void kernel_launch(void* const* d_in, const int* in_sizes, int n_in,
                              void* d_out, int out_size, void* d_ws, size_t ws_size,
                              hipStream_t stream) {
    const float* gene_emb = (const float*)d_in[0];
    const float* cell_emb = (const float*)d_in[1];
    const float* W_g2c    = (const float*)d_in[2];
    const float* b_g2c    = (const float*)d_in[3];
    const float* W_c2g    = (const float*)d_in[4];
    const float* b_c2g    = (const float*)d_in[5];
    const float* Wp       = (const float*)d_in[6];
    const float* bp       = (const float*)d_in[7];
    const int* g2c_src = (const int*)d_in[8];
    const int* g2c_dst = (const int*)d_in[9];
    const int* c2g_src = (const int*)d_in[10];
    const int* c2g_dst = (const int*)d_in[11];
    const int* dec_src = (const int*)d_in[12];
    const int* dec_dst = (const int*)d_in[13];

    int*   wsi = (int*)d_ws;
    float* wsf = (float*)d_ws;
    unsigned short* gene_bf = (unsigned short*)(wsi + A_GENE_BF);
    unsigned short* cell_bf = (unsigned short*)(wsi + A_CELL_BF);
    unsigned short* wt1     = (unsigned short*)(wsi + A_WT1_BF);
    unsigned short* wt2     = (unsigned short*)(wsi + A_WT2_BF);
    unsigned short* aggC    = (unsigned short*)(wsi + A_AGGC_BF);
    unsigned short* aggG    = (unsigned short*)(wsi + A_AGGG_BF);
    int2* sortC = (int2*)(wsi + A_SORT_C);
    int2* sortG = (int2*)(wsi + A_SORT_G);

    float* out = (float*)d_out;
    float* out_score = out;                      // [200000]
    float* out_hgene = out + NEDGE;              // [4762*256]
    float* out_hcell = out + NEDGE + N_GENE * D; // [847*256]

    // 1. hist (bin-major partials) + vectorized bf16 cvt / W transpose
    k_pre<<<2 * NPART, 1024, 0, stream>>>(g2c_src, g2c_dst, c2g_src, c2g_dst,
                                          gene_emb, cell_emb, W_g2c, W_c2g,
                                          wsi + A_PART, gene_bf, cell_bf, wt1, wt2);
    // 2. bin-major reduce: partial -> per-block exclusive ranks; deg, nrm
    k_reduce<<<(NBINS + 255) / 256, 256, 0, stream>>>(wsi + A_PART, wsi + A_DEG,
                                                      wsf + A_NRM);
    // 3. counting sort (per-block LDS offset scan; publishes global offs)
    {
        dim3 grid(NPART, 2);
        k_scatter<<<grid, 1024, 0, stream>>>(g2c_src, g2c_dst, c2g_src, c2g_dst,
                                             wsi + A_DEG, wsi + A_PART, wsf + A_NRM,
                                             wsi + A_OFFS_C, wsi + A_OFFS_G,
                                             sortC, sortG);
    }
    // 4. aggregate: block-per-cell + wave-per-gene, paired-row 16B loads
    k_agg<<<N_CELL + (N_GENE + 3) / 4, 256, 0, stream>>>(
        gene_bf, cell_bf, sortC, sortG, wsi + A_OFFS_C, wsi + A_OFFS_G,
        wsf + A_NRM, aggC, aggG);
    // 5. MFMA GEMMs + bias + relu + fused Wp row-dots
    {
        const int CT = (N_CELL + 15) / 16, GT = (N_GENE + 15) / 16;
        k_gemm2<<<(CT + GT + 3) / 4, 256, 0, stream>>>(aggC, aggG, wt1, wt2,
                                                       b_g2c, b_c2g, Wp,
                                                       out_hcell, out_hgene,
                                                       wsf + A_SG, wsf + A_SC);
    }
    // 6. edge scores
    k_score<<<(NEDGE + 255) / 256, 256, 0, stream>>>(dec_src, dec_dst,
                                                     wsf + A_SG, wsf + A_SC, bp, out_score);
}

// Round 14
// 158.835 us; speedup vs baseline: 1.6239x; 1.0745x over previous
//
#include <hip/hip_runtime.h>

#define N_GENE 4762
#define N_CELL 847
#define NEDGE  200000
#define D      256
#define NPART  64     // hist/scatter chunks

typedef __attribute__((ext_vector_type(8))) short short8;            // 8 bf16
typedef __attribute__((ext_vector_type(8))) unsigned short ushort8v; // 16B load
typedef __attribute__((ext_vector_type(4))) float f32x4;

// ---- histogram segment layout (bins, concatenated) ----
#define S_G_OUT 0                      // [4762] g2c_src degrees (genes)
#define S_C_IN  (S_G_OUT + N_GENE)     // [847]  g2c_dst degrees (cells)
#define S_C_OUT (S_C_IN + N_CELL)      // [847]  c2g_src degrees (cells)
#define S_G_IN  (S_C_OUT + N_CELL)     // [4762] c2g_dst degrees (genes)
#define NBINS   (S_G_IN + N_GENE)      // 11218

#define ALIGN8(x) (((x) + 7) & ~7)

// ---- workspace layout (4-byte slots) ----
// partial is ROW-MAJOR partial[b][j]: k_pre's writeback is coalesced, and
// k_reduce's per-b iteration is coalesced across threads (thread=bin).
// (Round 13 showed bin-major regresses: it scatters the writer.)
#define A_DEG      0                          // int[11218]
#define A_NRM      (A_DEG + NBINS)            // float[11218]
#define A_OFFS_C   (A_NRM + NBINS)            // int[848]
#define A_OFFS_G   (A_OFFS_C + N_CELL + 1)    // int[4763]
#define A_SORT_C   ALIGN8(A_OFFS_G + N_GENE + 1) // int2[200000]
#define A_SORT_G   (A_SORT_C + 2 * NEDGE)     // int2[200000]
#define A_PART     (A_SORT_G + 2 * NEDGE)     // int[64*11218]
#define A_SG       (A_PART + NPART * NBINS)   // float[4762]
#define A_SC       (A_SG + N_GENE)            // float[847]
// bf16 regions (ushort; slot = count/2), 16B-aligned
#define A_GENE_BF  ALIGN8(A_SC + N_CELL)
#define A_CELL_BF  ALIGN8(A_GENE_BF + N_GENE * D / 2)
#define A_WT1_BF   ALIGN8(A_CELL_BF + N_CELL * D / 2)
#define A_WT2_BF   ALIGN8(A_WT1_BF + D * D / 2)
#define A_AGGC_BF  ALIGN8(A_WT2_BF + D * D / 2)
#define A_AGGG_BF  ALIGN8(A_AGGC_BF + N_CELL * D / 2)

__device__ __forceinline__ unsigned short f2bf(float f) {
    unsigned u = __float_as_uint(f);
    u = (u + 0x7FFFu + ((u >> 16) & 1u)) >> 16;    // RNE
    return (unsigned short)u;
}
__device__ __forceinline__ float bf2f(unsigned short b) {
    return __uint_as_float(((unsigned)b) << 16);
}

// blocks 0..63: per-block LDS histograms -> partial[b][j]
// blocks 64..127: bf16 conversions + W transposes (independent work)
__global__ __launch_bounds__(1024) void k_pre(
        const int* __restrict__ g2c_src, const int* __restrict__ g2c_dst,
        const int* __restrict__ c2g_src, const int* __restrict__ c2g_dst,
        const float* __restrict__ gene_emb, const float* __restrict__ cell_emb,
        const float* __restrict__ W_g2c, const float* __restrict__ W_c2g,
        int* __restrict__ partial,
        unsigned short* __restrict__ gene_bf, unsigned short* __restrict__ cell_bf,
        unsigned short* __restrict__ wt1, unsigned short* __restrict__ wt2) {
    __shared__ int sh[NBINS];
    int B = blockIdx.x, T = threadIdx.x;
    if (B < NPART) {
        for (int j = T; j < NBINS; j += 1024) sh[j] = 0;
        __syncthreads();
        const int chunk = (NEDGE + NPART - 1) / NPART;
        int e0 = B * chunk, e1 = min(NEDGE, e0 + chunk);
        for (int e = e0 + T; e < e1; e += 1024) {
            atomicAdd(&sh[S_G_OUT + g2c_src[e]], 1);
            atomicAdd(&sh[S_C_IN  + g2c_dst[e]], 1);
            atomicAdd(&sh[S_C_OUT + c2g_src[e]], 1);
            atomicAdd(&sh[S_G_IN  + c2g_dst[e]], 1);
        }
        __syncthreads();
        int* pp = partial + B * NBINS;
        for (int j = T; j < NBINS; j += 1024) pp[j] = sh[j];
    } else {
        const int NG = N_GENE * D, NC = N_CELL * D, NW = D * D;
        const int total = NG + NC + 2 * NW;
        for (int i = (B - NPART) * 1024 + T; i < total; i += NPART * 1024) {
            if (i < NG) {
                gene_bf[i] = f2bf(gene_emb[i]);
            } else if (i < NG + NC) {
                int j = i - NG;
                cell_bf[j] = f2bf(cell_emb[j]);
            } else if (i < NG + NC + NW) {
                int j = i - NG - NC;
                wt1[j] = f2bf(W_g2c[(j & 255) * D + (j >> 8)]);
            } else {
                int j = i - NG - NC - NW;
                wt2[j] = f2bf(W_c2g[(j & 255) * D + (j >> 8)]);
            }
        }
    }
}

// deg[j] = sum_b partial[b][j]; partial[b][j] := exclusive prefix over b;
// nrm[j] = rsqrt(max(deg,1)). Thread=bin; each b-iteration is coalesced.
__global__ void k_reduce(int* __restrict__ partial, int* __restrict__ deg,
                         float* __restrict__ nrm) {
    int j = blockIdx.x * blockDim.x + threadIdx.x;
    if (j < NBINS) {
        int s = 0;
        #pragma unroll
        for (int b0 = 0; b0 < NPART; b0 += 32) {
            int t[32];
            #pragma unroll
            for (int u = 0; u < 32; u++) t[u] = partial[(b0 + u) * NBINS + j];
            #pragma unroll
            for (int u = 0; u < 32; u++) { partial[(b0 + u) * NBINS + j] = s; s += t[u]; }
        }
        deg[j] = s;
        nrm[j] = rsqrtf(fmaxf((float)s, 1.0f));
    }
}

// Deterministic counting sort; each block recomputes the CSR-offset scan of its
// direction's degree segment in LDS, seeds cursors with offs+base_rank,
// places int2{src, norm_src}. grid=(NPART, 2).
__global__ __launch_bounds__(1024) void k_scatter(
        const int* __restrict__ g2c_src, const int* __restrict__ g2c_dst,
        const int* __restrict__ c2g_src, const int* __restrict__ c2g_dst,
        const int* __restrict__ deg, const int* __restrict__ partial,
        const float* __restrict__ nrm,
        int* __restrict__ offsC, int* __restrict__ offsG,
        int2* __restrict__ sortC, int2* __restrict__ sortG) {
    __shared__ int soffs[N_GENE + 1];
    __shared__ int scur[N_GENE];
    __shared__ int wsum[16];
    int T = threadIdx.x, blk = blockIdx.x, dir = blockIdx.y;
    const int* src  = dir ? c2g_src : g2c_src;
    const int* dst  = dir ? c2g_dst : g2c_dst;
    const int* dgs  = dir ? deg + S_G_IN : deg + S_C_IN;
    const float* nsv = dir ? nrm + S_C_OUT : nrm + S_G_OUT;
    int seg         = dir ? S_G_IN : S_C_IN;
    int nb          = dir ? N_GENE : N_CELL;
    int* goffs      = dir ? offsG : offsC;
    int2* sorted    = dir ? sortG : sortC;
    int per = (nb + 1023) >> 10;              // <=5
    int i0 = T * per, i1 = min(nb, i0 + per);
    int loc[5];
    int s = 0;
    for (int i = i0; i < i1; i++) { loc[i - i0] = s; s += dgs[i]; }
    int lane = T & 63, w = T >> 6;
    int t = s;
    #pragma unroll
    for (int off = 1; off < 64; off <<= 1) {
        int u = __shfl_up(t, off);
        if (lane >= off) t += u;
    }
    if (lane == 63) wsum[w] = t;
    __syncthreads();
    if (w == 0 && lane < 16) {
        int x = wsum[lane];
        #pragma unroll
        for (int off = 1; off < 16; off <<= 1) {
            int u = __shfl_up(x, off);
            if (lane >= off) x += u;
        }
        wsum[lane] = x;
    }
    __syncthreads();
    int wbase = w ? wsum[w - 1] : 0;
    int excl = wbase + t - s;
    for (int i = i0; i < i1; i++) soffs[i] = excl + loc[i - i0];
    if (T == 1023) soffs[nb] = excl + s;
    __syncthreads();
    if (blk == 0)
        for (int j = T; j <= nb; j += 1024) goffs[j] = soffs[j];
    const int* basep = partial + blk * NBINS + seg;
    for (int j = T; j < nb; j += 1024) scur[j] = soffs[j] + basep[j];
    __syncthreads();
    const int chunk = (NEDGE + NPART - 1) / NPART;
    int e0 = blk * chunk, e1 = min(NEDGE, e0 + chunk);
    for (int e = e0 + T; e < e1; e += 1024) {
        int d = dst[e], sv = src[e];
        float nv = nsv[sv];
        int pos = atomicAdd(&scur[d], 1);
        sorted[pos] = make_int2(sv, __float_as_int(nv));
    }
}

// Aggregation with paired-row 16B loads: lane = (half = lane>>5, li = lane&31);
// one ushort8 load fetches 2 edge rows per instruction, lane owns 8 columns;
// xor-32 shuffle folds the halves. Blocks 0..846: block-per-cell. Rest: wave-per-gene.
__global__ __launch_bounds__(256) void k_agg(
        const unsigned short* __restrict__ gene_bf,
        const unsigned short* __restrict__ cell_bf,
        const int2* __restrict__ sortC, const int2* __restrict__ sortG,
        const int* __restrict__ offsC, const int* __restrict__ offsG,
        const float* __restrict__ nrm,
        unsigned short* __restrict__ aggC, unsigned short* __restrict__ aggG) {
    __shared__ int   sidx[4][64];
    __shared__ float snrm[4][64];
    __shared__ float pacc[4][256];
    int w = threadIdx.x >> 6, lane = threadIdx.x & 63;
    int half = lane >> 5, li = lane & 31;
    int B = blockIdx.x;
    bool isCell = B < N_CELL;

    int e0, e1;
    const unsigned short* emb;
    const int2* sorted;
    int node;
    if (isCell) {
        node = B;
        int f0 = offsC[node], f1 = offsC[node + 1];
        int ne = f1 - f0, nw = (ne + 3) >> 2;
        e0 = f0 + w * nw; e1 = min(f1, e0 + nw);
        emb = gene_bf; sorted = sortC;
    } else {
        node = (B - N_CELL) * 4 + w;
        if (node >= N_GENE) return;
        e0 = offsG[node]; e1 = offsG[node + 1];
        emb = cell_bf; sorted = sortG;
    }

    float acc[8];
    #pragma unroll
    for (int c = 0; c < 8; c++) acc[c] = 0.f;

    for (int base = e0; base < e1; base += 64) {
        int n = min(64, e1 - base);
        if (lane < n) {
            int2 pr = sorted[base + lane];
            sidx[w][lane] = pr.x;
            snrm[w][lane] = __int_as_float(pr.y);
        }
        // same-wave LDS write->read: program order, no barrier needed
        int i = 0;
        for (; 2 * i + 8 <= n; i += 4) {
            int j0 = 2 * i + half, j1 = 2 * i + 2 + half;
            int j2 = 2 * i + 4 + half, j3 = 2 * i + 6 + half;
            ushort8v v0 = *(const ushort8v*)&emb[sidx[w][j0] * D + li * 8];
            ushort8v v1 = *(const ushort8v*)&emb[sidx[w][j1] * D + li * 8];
            ushort8v v2 = *(const ushort8v*)&emb[sidx[w][j2] * D + li * 8];
            ushort8v v3 = *(const ushort8v*)&emb[sidx[w][j3] * D + li * 8];
            float n0 = snrm[w][j0], n1 = snrm[w][j1];
            float n2 = snrm[w][j2], n3 = snrm[w][j3];
            #pragma unroll
            for (int c = 0; c < 8; c++)
                acc[c] += bf2f(v0[c]) * n0 + bf2f(v1[c]) * n1 +
                          bf2f(v2[c]) * n2 + bf2f(v3[c]) * n3;
        }
        int npair = (n + 1) >> 1;
        for (; i < npair; i++) {
            int jj = 2 * i + half;
            bool ok = jj < n;
            int idx = ok ? sidx[w][jj] : sidx[w][0];
            float nv = ok ? snrm[w][jj] : 0.f;
            ushort8v v = *(const ushort8v*)&emb[idx * D + li * 8];
            #pragma unroll
            for (int c = 0; c < 8; c++) acc[c] += bf2f(v[c]) * nv;
        }
    }
    #pragma unroll
    for (int c = 0; c < 8; c++) acc[c] += __shfl_xor(acc[c], 32);

    if (isCell) {
        if (half == 0) {
            #pragma unroll
            for (int c = 0; c < 8; c++) pacc[w][li * 8 + c] = acc[c];
        }
        __syncthreads();
        int T = threadIdx.x;          // T = column
        float s2 = pacc[0][T] + pacc[1][T] + pacc[2][T] + pacc[3][T];
        aggC[node * D + T] = f2bf(s2 * nrm[S_C_IN + node]);
    } else {
        if (half == 0) {
            float ndv = nrm[S_G_IN + node];
            ushort8v o;
            #pragma unroll
            for (int c = 0; c < 8; c++) o[c] = f2bf(acc[c] * ndv);
            *(ushort8v*)&aggG[node * D + li * 8] = o;
        }
    }
}

// MFMA bf16 GEMM, both directions: H = relu(Agg @ W + b), fused Wp row-dot.
__global__ __launch_bounds__(256) void k_gemm2(
        const unsigned short* __restrict__ aggC, const unsigned short* __restrict__ aggG,
        const unsigned short* __restrict__ wt1, const unsigned short* __restrict__ wt2,
        const float* __restrict__ b_g2c, const float* __restrict__ b_c2g,
        const float* __restrict__ Wp,
        float* __restrict__ hC, float* __restrict__ hG,
        float* __restrict__ sg, float* __restrict__ sc) {
    const int CT = (N_CELL + 15) / 16;   // 53
    const int GT = (N_GENE + 15) / 16;   // 298
    int wid = blockIdx.x * 4 + (threadIdx.x >> 6);
    if (wid >= CT + GT) return;
    bool isCell = wid < CT;
    int tile = isCell ? wid : wid - CT;
    int m0 = tile * 16;
    int M = isCell ? N_CELL : N_GENE;
    const unsigned short* A  = isCell ? aggC : aggG;
    const unsigned short* Wt = isCell ? wt1 : wt2;
    const float* bias = isCell ? b_g2c : b_c2g;
    const float* wp   = isCell ? Wp + D : Wp;
    float* H  = isCell ? hC : hG;
    float* sv = isCell ? sc : sg;
    int lane = threadIdx.x & 63;
    int l15 = lane & 15, quad = lane >> 4;
    int arow = m0 + l15;
    if (arow >= M) arow = M - 1;
    f32x4 acc[16];
    #pragma unroll
    for (int t = 0; t < 16; t++) acc[t] = (f32x4){0.f, 0.f, 0.f, 0.f};
    #pragma unroll
    for (int k0 = 0; k0 < D; k0 += 32) {
        short8 a = *(const short8*)&A[arow * D + k0 + quad * 8];
        #pragma unroll
        for (int t = 0; t < 16; t++) {
            short8 b = *(const short8*)&Wt[(t * 16 + l15) * D + k0 + quad * 8];
            acc[t] = __builtin_amdgcn_mfma_f32_16x16x32_bf16(a, b, acc[t], 0, 0, 0);
        }
    }
    float dot[4] = {0.f, 0.f, 0.f, 0.f};
    #pragma unroll
    for (int t = 0; t < 16; t++) {
        int col = t * 16 + l15;
        float bv = bias[col], wv = wp[col];
        #pragma unroll
        for (int r = 0; r < 4; r++) {
            int row = m0 + quad * 4 + r;
            float h = fmaxf(acc[t][r] + bv, 0.f);
            if (row < M) H[row * D + col] = h;
            dot[r] += h * wv;
        }
    }
    #pragma unroll
    for (int off = 1; off < 16; off <<= 1) {
        #pragma unroll
        for (int r = 0; r < 4; r++) dot[r] += __shfl_xor(dot[r], off);
    }
    if (l15 == 0) {
        #pragma unroll
        for (int r = 0; r < 4; r++) {
            int row = m0 + quad * 4 + r;
            if (row < M) sv[row] = dot[r];
        }
    }
}

__global__ void k_score(const int* __restrict__ dsrc, const int* __restrict__ ddst,
                        const float* __restrict__ sg, const float* __restrict__ sc,
                        const float* __restrict__ bp, float* __restrict__ out) {
    int i = blockIdx.x * blockDim.x + threadIdx.x;
    if (i < NEDGE) out[i] = sg[dsrc[i]] + sc[ddst[i]] + bp[0];
}

extern "C" void kernel_launch(void* const* d_in, const int* in_sizes, int n_in,
                              void* d_out, int out_size, void* d_ws, size_t ws_size,
                              hipStream_t stream) {
    const float* gene_emb = (const float*)d_in[0];
    const float* cell_emb = (const float*)d_in[1];
    const float* W_g2c    = (const float*)d_in[2];
    const float* b_g2c    = (const float*)d_in[3];
    const float* W_c2g    = (const float*)d_in[4];
    const float* b_c2g    = (const float*)d_in[5];
    const float* Wp       = (const float*)d_in[6];
    const float* bp       = (const float*)d_in[7];
    const int* g2c_src = (const int*)d_in[8];
    const int* g2c_dst = (const int*)d_in[9];
    const int* c2g_src = (const int*)d_in[10];
    const int* c2g_dst = (const int*)d_in[11];
    const int* dec_src = (const int*)d_in[12];
    const int* dec_dst = (const int*)d_in[13];

    int*   wsi = (int*)d_ws;
    float* wsf = (float*)d_ws;
    unsigned short* gene_bf = (unsigned short*)(wsi + A_GENE_BF);
    unsigned short* cell_bf = (unsigned short*)(wsi + A_CELL_BF);
    unsigned short* wt1     = (unsigned short*)(wsi + A_WT1_BF);
    unsigned short* wt2     = (unsigned short*)(wsi + A_WT2_BF);
    unsigned short* aggC    = (unsigned short*)(wsi + A_AGGC_BF);
    unsigned short* aggG    = (unsigned short*)(wsi + A_AGGG_BF);
    int2* sortC = (int2*)(wsi + A_SORT_C);
    int2* sortG = (int2*)(wsi + A_SORT_G);

    float* out = (float*)d_out;
    float* out_score = out;                      // [200000]
    float* out_hgene = out + NEDGE;              // [4762*256]
    float* out_hcell = out + NEDGE + N_GENE * D; // [847*256]

    // 1. hist (blocks 0..63) + bf16 cvt / W transpose (blocks 64..127)
    k_pre<<<2 * NPART, 1024, 0, stream>>>(g2c_src, g2c_dst, c2g_src, c2g_dst,
                                          gene_emb, cell_emb, W_g2c, W_c2g,
                                          wsi + A_PART, gene_bf, cell_bf, wt1, wt2);
    // 2. reduce partials -> deg, nrm; partial := per-block exclusive base ranks
    k_reduce<<<(NBINS + 255) / 256, 256, 0, stream>>>(wsi + A_PART, wsi + A_DEG,
                                                      wsf + A_NRM);
    // 3. counting sort (per-block LDS offset scan; publishes global offs)
    {
        dim3 grid(NPART, 2);
        k_scatter<<<grid, 1024, 0, stream>>>(g2c_src, g2c_dst, c2g_src, c2g_dst,
                                             wsi + A_DEG, wsi + A_PART, wsf + A_NRM,
                                             wsi + A_OFFS_C, wsi + A_OFFS_G,
                                             sortC, sortG);
    }
    // 4. aggregate: block-per-cell + wave-per-gene, paired-row 16B loads
    k_agg<<<N_CELL + (N_GENE + 3) / 4, 256, 0, stream>>>(
        gene_bf, cell_bf, sortC, sortG, wsi + A_OFFS_C, wsi + A_OFFS_G,
        wsf + A_NRM, aggC, aggG);
    // 5. MFMA GEMMs + bias + relu + fused Wp row-dots
    {
        const int CT = (N_CELL + 15) / 16, GT = (N_GENE + 15) / 16;
        k_gemm2<<<(CT + GT + 3) / 4, 256, 0, stream>>>(aggC, aggG, wt1, wt2,
                                                       b_g2c, b_c2g, Wp,
                                                       out_hcell, out_hgene,
                                                       wsf + A_SG, wsf + A_SC);
    }
    // 6. edge scores
    k_score<<<(NEDGE + 255) / 256, 256, 0, stream>>>(dec_src, dec_dst,
                                                     wsf + A_SG, wsf + A_SC, bp, out_score);
}